// Round 3
// baseline (392.405 us; speedup 1.0000x reference)
//
#include <hip/hip_runtime.h>
#include <hip/hip_bf16.h>

// TriangleMultiplicativeModule (ingoing) — B=1, N=512, D=H=128
// R3: LN1 split back out (streaming); k_proj barrier-free (A+B direct->VGPR,
//     no LDS, waves fully independent); einsum 128^2 tiles with XCD plane
//     locality + conflict-free padded LDS.

#define NSEQ 512
#define NN 262144        // 512*512
#define DMODEL 128

typedef __attribute__((ext_vector_type(8))) short short8;
typedef __attribute__((ext_vector_type(4))) float f32x4;

__device__ __forceinline__ unsigned short f2b(float f) {
    __hip_bfloat16 h = __float2bfloat16(f);
    return *reinterpret_cast<unsigned short*>(&h);
}
__device__ __forceinline__ float b2f(unsigned short u) {
    __hip_bfloat16 h;
    *reinterpret_cast<unsigned short*>(&h) = u;
    return __bfloat162float(h);
}
__device__ __forceinline__ float sigmoidf_(float x) {
    return 1.0f / (1.0f + __expf(-x));
}

// ---------------------------------------------------------------------------
// All 6 weight transposes in one launch: w[k][h] fp32 -> wt[mat][h][k] bf16
// ---------------------------------------------------------------------------
__global__ __launch_bounds__(256) void k_wt_all(
    const float* __restrict__ w0, const float* __restrict__ w1,
    const float* __restrict__ w2, const float* __restrict__ w3,
    const float* __restrict__ w4, const float* __restrict__ w5,
    unsigned short* __restrict__ wt) {
    int bid = blockIdx.x;
    int mat = bid >> 6;
    const float* w = (mat == 0) ? w0 : (mat == 1) ? w1 : (mat == 2) ? w2
                   : (mat == 3) ? w3 : (mat == 4) ? w4 : w5;
    int idx = (bid & 63) * 256 + threadIdx.x;   // 0..16383
    int d = idx >> 7, h = idx & 127;
    wt[mat * 16384 + h * 128 + d] = f2b(w[idx]);
}

// ---------------------------------------------------------------------------
// LN1 streaming: 2 rows per wave (32 lanes each), float4/lane in, 4xbf16 out.
// ---------------------------------------------------------------------------
__global__ __launch_bounds__(256) void k_ln1(const float* __restrict__ x,
                                             const float* __restrict__ sc,
                                             const float* __restrict__ bi,
                                             unsigned short* __restrict__ xn) {
    int t = threadIdx.x;
    int l = t & 31;
    size_t row = (size_t)blockIdx.x * 8 + (t >> 5);
    float4 v = *(const float4*)(x + row * DMODEL + l * 4);
    float s  = v.x + v.y + v.z + v.w;
    float sq = v.x * v.x + v.y * v.y + v.z * v.z + v.w * v.w;
    #pragma unroll
    for (int m = 1; m < 32; m <<= 1) {   // stays within each 32-lane half
        s  += __shfl_xor(s, m);
        sq += __shfl_xor(sq, m);
    }
    float mean = s * (1.f / 128.f);
    float var  = sq * (1.f / 128.f) - mean * mean;
    float inv  = rsqrtf(var + 1e-6f);
    float4 scv = *(const float4*)(sc + l * 4);
    float4 biv = *(const float4*)(bi + l * 4);
    unsigned long long o = 0;
    o |= (unsigned long long)f2b((v.x - mean) * inv * scv.x + biv.x);
    o |= (unsigned long long)f2b((v.y - mean) * inv * scv.y + biv.y) << 16;
    o |= (unsigned long long)f2b((v.z - mean) * inv * scv.z + biv.z) << 32;
    o |= (unsigned long long)f2b((v.w - mean) * inv * scv.w + biv.w) << 48;
    *(unsigned long long*)(xn + row * DMODEL + l * 4) = o;
}

// ---------------------------------------------------------------------------
// Barrier-free projections. Block (a0,b): 4 independent waves, wave = 64 rows
// x 32 h. A-frags direct global->VGPR from xn (L3-resident); B-frags direct
// from wt (L2-resident), double-buffered. No LDS, no __syncthreads.
// ---------------------------------------------------------------------------
__global__ __launch_bounds__(256, 2) void k_proj(
    const unsigned short* __restrict__ xn,
    const float* __restrict__ src_mask,
    const unsigned short* __restrict__ wt,  // wl,wlg,wr,wrg,wog (16384 each)
    const float* __restrict__ bl,  const float* __restrict__ blg,
    const float* __restrict__ br,  const float* __restrict__ brg,
    const float* __restrict__ bog,
    unsigned short* __restrict__ left_t,
    unsigned short* __restrict__ right_t,
    unsigned short* __restrict__ og) {
    const int t = threadIdx.x;
    const int lane = t & 63;
    const int wv = t >> 6;
    const int a0 = blockIdx.x * 64;
    const int b  = blockIdx.y;
    const int n0 = wv * 32;

    short8 bfA[2][4], bfB[2][4];
    auto loadB = [&](short8 (&dst)[2][4], int mat) {
        const unsigned short* base = wt + mat * 16384 + (lane >> 4) * 8;
        #pragma unroll
        for (int nf = 0; nf < 2; ++nf)
            #pragma unroll
            for (int kc = 0; kc < 4; ++kc)
                dst[nf][kc] = *(const short8*)(
                    base + (n0 + nf * 16 + (lane & 15)) * 128 + kc * 32);
    };
    loadB(bfA, 0);
    loadB(bfB, 1);

    // A fragments direct from global (shared logically across waves; L2/L3 hit)
    short8 af[4][4];   // [mf][kc]
    {
        const unsigned short* abase =
            xn + ((size_t)(a0 + (lane & 15)) * NSEQ + b) * DMODEL + (lane >> 4) * 8;
        #pragma unroll
        for (int mf = 0; mf < 4; ++mf)
            #pragma unroll
            for (int kc = 0; kc < 4; ++kc)
                af[mf][kc] = *(const short8*)(abase + (size_t)mf * 16 * NSEQ * DMODEL + kc * 32);
    }

    f32x4 acc0[4][2], acc1[4][2];
    float smb = src_mask[b];

    auto mmat = [&](f32x4 (&acc)[4][2], short8 (&bf)[2][4]) {
        #pragma unroll
        for (int mf = 0; mf < 4; ++mf)
            #pragma unroll
            for (int nf = 0; nf < 2; ++nf)
                acc[mf][nf] = f32x4{0.f, 0.f, 0.f, 0.f};
        #pragma unroll
        for (int kc = 0; kc < 4; ++kc)
            #pragma unroll
            for (int mf = 0; mf < 4; ++mf)
                #pragma unroll
                for (int nf = 0; nf < 2; ++nf)
                    acc[mf][nf] = __builtin_amdgcn_mfma_f32_16x16x32_bf16(
                        af[mf][kc], bf[nf][kc], acc[mf][nf], 0, 0, 0);
    };
    auto epi_pair = [&](const float* b1, const float* b2, unsigned short* dst) {
        #pragma unroll
        for (int nf = 0; nf < 2; ++nf) {
            int h = n0 + nf * 16 + (lane & 15);
            float b1v = b1[h], b2v = b2[h];
            #pragma unroll
            for (int mf = 0; mf < 4; ++mf) {
                int abase = a0 + mf * 16 + ((lane >> 4) << 2);
                unsigned long long pv64 = 0;
                #pragma unroll
                for (int j = 0; j < 4; ++j) {
                    float pv = acc0[mf][nf][j] + b1v;
                    float gv = acc1[mf][nf][j] + b2v;
                    float mk = src_mask[abase + j] * smb;
                    unsigned long long q = f2b(pv * mk * sigmoidf_(gv));
                    pv64 |= q << (16 * j);
                }
                *(unsigned long long*)(dst + (size_t)h * NN + (size_t)b * NSEQ + abase) = pv64;
            }
        }
    };

    // order: 0=wl(acc0) 1=wlg(acc1) -> left; 2=wr 3=wrg -> right; 4=wog
    mmat(acc0, bfA);
    loadB(bfA, 2);
    mmat(acc1, bfB);
    loadB(bfB, 3);
    epi_pair(bl, blg, left_t);
    mmat(acc0, bfA);
    loadB(bfA, 4);
    mmat(acc1, bfB);
    epi_pair(br, brg, right_t);
    mmat(acc0, bfA);
    #pragma unroll
    for (int nf = 0; nf < 2; ++nf) {
        int h = n0 + nf * 16 + (lane & 15);
        float bv = bog[h];
        #pragma unroll
        for (int mf = 0; mf < 4; ++mf) {
            int abase = a0 + mf * 16 + ((lane >> 4) << 2);
            #pragma unroll
            for (int j = 0; j < 4; ++j) {
                float ov = sigmoidf_(acc0[mf][nf][j] + bv);
                og[((size_t)(abase + j) * NSEQ + b) * DMODEL + h] = f2b(ov);
            }
        }
    }
}

// ---------------------------------------------------------------------------
// Einsum: per d-plane GEMM C[i][j] = sum_k A[i][k]*B[j][k].
// 128x128 tile, BK=32, padded LDS stride 36 (conflict-free), XCD-chunked
// swizzle so each plane's 16 tiles share one XCD's L2.
// ---------------------------------------------------------------------------
__global__ __launch_bounds__(256) void k_einsum(
    const unsigned short* __restrict__ lt,
    const unsigned short* __restrict__ rt,
    unsigned short* __restrict__ mid) {
    __shared__ __align__(16) unsigned short As[128 * 36];
    __shared__ __align__(16) unsigned short Bs[128 * 36];
    const int t = threadIdx.x, lane = t & 63, wv = t >> 6;
    // swizzle: 2048 blocks; XCD = bid%8 (HW round-robin). Give each XCD 16
    // whole planes: plane = xcd*16 + slot/16, tile = slot%16.
    const int bid = blockIdx.x;
    const int xcd = bid & 7, slot = bid >> 3;
    const int d = xcd * 16 + (slot >> 4);
    const int tile = slot & 15;
    const int i0 = (tile >> 2) * 128, j0 = (tile & 3) * 128;
    const int m0 = (wv >> 1) * 64, n0 = (wv & 1) * 64;
    const unsigned short* Ag = lt + (size_t)d * NN;
    const unsigned short* Bg = rt + (size_t)d * NN;

    f32x4 acc[4][4];
    #pragma unroll
    for (int mf = 0; mf < 4; ++mf)
        #pragma unroll
        for (int nf = 0; nf < 4; ++nf)
            acc[mf][nf] = f32x4{0.f, 0.f, 0.f, 0.f};

    for (int k0 = 0; k0 < NSEQ; k0 += 32) {
        __syncthreads();
        #pragma unroll
        for (int it = 0; it < 2; ++it) {
            int c = it * 256 + t;          // 16B chunk id, 0..511
            int row = c >> 2, sub = c & 3;
            *(short8*)(&As[row * 36 + sub * 8]) =
                *(const short8*)(Ag + (size_t)(i0 + row) * NSEQ + k0 + sub * 8);
            *(short8*)(&Bs[row * 36 + sub * 8]) =
                *(const short8*)(Bg + (size_t)(j0 + row) * NSEQ + k0 + sub * 8);
        }
        __syncthreads();
        int ko = (lane >> 4) * 8;
        short8 af[4], bf[4];
        #pragma unroll
        for (int mf = 0; mf < 4; ++mf)
            af[mf] = *(const short8*)(&As[(m0 + mf * 16 + (lane & 15)) * 36 + ko]);
        #pragma unroll
        for (int nf = 0; nf < 4; ++nf)
            bf[nf] = *(const short8*)(&Bs[(n0 + nf * 16 + (lane & 15)) * 36 + ko]);
        #pragma unroll
        for (int mf = 0; mf < 4; ++mf)
            #pragma unroll
            for (int nf = 0; nf < 4; ++nf)
                acc[mf][nf] = __builtin_amdgcn_mfma_f32_16x16x32_bf16(
                    af[mf], bf[nf], acc[mf][nf], 0, 0, 0);
    }
    unsigned short* out = mid + (size_t)d * NN;
    #pragma unroll
    for (int mf = 0; mf < 4; ++mf) {
        int rbase = i0 + m0 + mf * 16 + ((lane >> 4) << 2);
        #pragma unroll
        for (int nf = 0; nf < 4; ++nf) {
            int col = j0 + n0 + nf * 16 + (lane & 15);
            #pragma unroll
            for (int j = 0; j < 4; ++j)
                out[(size_t)(rbase + j) * NSEQ + col] = f2b(acc[mf][nf][j]);
        }
    }
}

// ---------------------------------------------------------------------------
// LN2*gate. Thread = position; whole 128-d row in 64 packed VGPRs (mid read
// once, coalesced). Output via LDS for contiguous coalesced stores.
// ---------------------------------------------------------------------------
__global__ __launch_bounds__(128) void k_ln2gate(
    const unsigned short* __restrict__ mid,
    const unsigned short* __restrict__ og,
    const float* __restrict__ sc, const float* __restrict__ bi,
    unsigned short* __restrict__ g) {
    __shared__ __align__(16) unsigned short lo[128 * 136];
    const int t = threadIdx.x;
    const size_t p0 = (size_t)blockIdx.x * 128;
    const size_t p = p0 + t;

    unsigned int vals[64];
    float s = 0.f, sq = 0.f;
    #pragma unroll
    for (int d2 = 0; d2 < 64; ++d2) {
        unsigned int a = mid[(size_t)(2 * d2)     * NN + p];
        unsigned int c = mid[(size_t)(2 * d2 + 1) * NN + p];
        vals[d2] = a | (c << 16);
        float fa = b2f((unsigned short)a), fc = b2f((unsigned short)c);
        s += fa + fc; sq += fa * fa + fc * fc;
    }
    float mean = s * (1.f / 128.f);
    float var  = sq * (1.f / 128.f) - mean * mean;
    float inv  = rsqrtf(var + 1e-6f);
    #pragma unroll
    for (int c = 0; c < 16; ++c) {
        short8 ov = *(const short8*)(og + p * DMODEL + c * 8);
        short8 r8;
        #pragma unroll
        for (int e = 0; e < 8; ++e) {
            int d = c * 8 + e;
            unsigned int w = vals[d >> 1];
            float v = b2f((unsigned short)((d & 1) ? (w >> 16) : (w & 0xffff)));
            float y = (v - mean) * inv * sc[d] + bi[d];
            r8[e] = (short)f2b(y * b2f((unsigned short)ov[e]));
        }
        *(short8*)(&lo[t * 136 + c * 8]) = r8;
    }
    __syncthreads();
    #pragma unroll
    for (int i = 0; i < 16; ++i) {
        int idx = i * 128 + t;
        int row = idx >> 4, ch = idx & 15;
        *(short8*)(g + (p0 + row) * DMODEL + ch * 8) =
            *(const short8*)(&lo[row * 136 + ch * 8]);
    }
}

// ---------------------------------------------------------------------------
// Output projection: out = g @ wo + bo (fp32 out). 64-row tiles, full N=128.
// ---------------------------------------------------------------------------
__global__ __launch_bounds__(256) void k_out(
    const unsigned short* __restrict__ g,
    const unsigned short* __restrict__ wt_o,
    const float* __restrict__ bo,
    float* __restrict__ out) {
    __shared__ __align__(16) unsigned short As[64 * 136];
    __shared__ __align__(16) unsigned short Bs[128 * 136];
    const int t = threadIdx.x, lane = t & 63, wv = t >> 6;
    const size_t r0 = (size_t)blockIdx.x * 64;
    const int n0 = wv * 32;
    for (int it = 0; it < 4; ++it) {
        int idx = it * 256 + t;
        int row = idx >> 4, c = idx & 15;
        *(short8*)(&As[row * 136 + c * 8]) =
            *(const short8*)(g + (r0 + row) * DMODEL + c * 8);
    }
    for (int it = 0; it < 8; ++it) {
        int idx = it * 256 + t;
        int h = idx >> 4, c = idx & 15;
        *(short8*)(&Bs[h * 136 + c * 8]) = *(const short8*)(wt_o + h * 128 + c * 8);
    }
    __syncthreads();
    f32x4 acc[4][2];
    #pragma unroll
    for (int mf = 0; mf < 4; ++mf)
        #pragma unroll
        for (int nf = 0; nf < 2; ++nf)
            acc[mf][nf] = f32x4{0.f, 0.f, 0.f, 0.f};
    #pragma unroll
    for (int kc = 0; kc < 4; ++kc) {
        int ko = kc * 32 + (lane >> 4) * 8;
        short8 af[4], bf[2];
        #pragma unroll
        for (int mf = 0; mf < 4; ++mf)
            af[mf] = *(const short8*)(&As[(mf * 16 + (lane & 15)) * 136 + ko]);
        #pragma unroll
        for (int nf = 0; nf < 2; ++nf)
            bf[nf] = *(const short8*)(&Bs[(n0 + nf * 16 + (lane & 15)) * 136 + ko]);
        #pragma unroll
        for (int mf = 0; mf < 4; ++mf)
            #pragma unroll
            for (int nf = 0; nf < 2; ++nf)
                acc[mf][nf] = __builtin_amdgcn_mfma_f32_16x16x32_bf16(
                    af[mf], bf[nf], acc[mf][nf], 0, 0, 0);
    }
    #pragma unroll
    for (int nf = 0; nf < 2; ++nf) {
        int n = n0 + nf * 16 + (lane & 15);
        float bv = bo[n];
        #pragma unroll
        for (int mf = 0; mf < 4; ++mf) {
            int rb = mf * 16 + ((lane >> 4) << 2);
            #pragma unroll
            for (int j = 0; j < 4; ++j)
                out[(r0 + rb + j) * DMODEL + n] = acc[mf][nf][j] + bv;
        }
    }
}

// ---------------------------------------------------------------------------
extern "C" void kernel_launch(void* const* d_in, const int* in_sizes, int n_in,
                              void* d_out, int out_size, void* d_ws, size_t ws_size,
                              hipStream_t stream) {
    const float* x    = (const float*)d_in[0];
    const float* sm   = (const float*)d_in[1];
    const float* ln1s = (const float*)d_in[2];
    const float* ln1b = (const float*)d_in[3];
    const float* wl   = (const float*)d_in[4];
    const float* bl   = (const float*)d_in[5];
    const float* wr   = (const float*)d_in[6];
    const float* br   = (const float*)d_in[7];
    const float* wlg  = (const float*)d_in[8];
    const float* blg  = (const float*)d_in[9];
    const float* wrg  = (const float*)d_in[10];
    const float* brg  = (const float*)d_in[11];
    const float* wog  = (const float*)d_in[12];
    const float* bog  = (const float*)d_in[13];
    const float* ln2s = (const float*)d_in[14];
    const float* ln2b = (const float*)d_in[15];
    const float* wo   = (const float*)d_in[16];
    const float* bo   = (const float*)d_in[17];
    float* out = (float*)d_out;

    // workspace: wt(196608B) | xn | lt | rt | og | mid   (5 x 64MB)
    char* ws = (char*)d_ws;
    unsigned short* wt  = (unsigned short*)ws;
    unsigned short* xn  = (unsigned short*)(ws + 196608);
    unsigned short* lt  = (unsigned short*)(ws + 196608 + 1ull * 67108864);
    unsigned short* rt  = (unsigned short*)(ws + 196608 + 2ull * 67108864);
    unsigned short* ogb = (unsigned short*)(ws + 196608 + 3ull * 67108864);
    unsigned short* mid = (unsigned short*)(ws + 196608 + 4ull * 67108864);
    unsigned short* gb  = xn;   // reuse: xn dead after k_proj

    k_wt_all<<<384, 256, 0, stream>>>(wl, wlg, wr, wrg, wog, wo, wt);
    k_ln1<<<32768, 256, 0, stream>>>(x, ln1s, ln1b, xn);
    k_proj<<<dim3(8, 512), 256, 0, stream>>>(xn, sm, wt,
                                             bl, blg, br, brg, bog, lt, rt, ogb);
    k_einsum<<<2048, 256, 0, stream>>>(lt, rt, mid);
    k_ln2gate<<<2048, 128, 0, stream>>>(mid, ogb, ln2s, ln2b, gb);
    k_out<<<4096, 256, 0, stream>>>(gb, wt + 5 * 16384, bo, out);
}

// Round 4
// 320.179 us; speedup vs baseline: 1.2256x; 1.2256x over previous
//
#include <hip/hip_runtime.h>
#include <hip/hip_bf16.h>

// TriangleMultiplicativeModule (ingoing) — B=1, N=512, D=H=128
// R4: k_proj = A-tile in padded LDS (1 barrier) + B direct->VGPR (dbuf) +
//     og via LDS for full-line stores. k_einsum = double-buffered LDS,
//     1 barrier/iter, loads issued before compute.

#define NSEQ 512
#define NN 262144        // 512*512
#define DMODEL 128

typedef __attribute__((ext_vector_type(8))) short short8;
typedef __attribute__((ext_vector_type(4))) float f32x4;

__device__ __forceinline__ unsigned short f2b(float f) {
    __hip_bfloat16 h = __float2bfloat16(f);
    return *reinterpret_cast<unsigned short*>(&h);
}
__device__ __forceinline__ float b2f(unsigned short u) {
    __hip_bfloat16 h;
    *reinterpret_cast<unsigned short*>(&h) = u;
    return __bfloat162float(h);
}
__device__ __forceinline__ float sigmoidf_(float x) {
    return 1.0f / (1.0f + __expf(-x));
}

// ---------------------------------------------------------------------------
// All 6 weight transposes in one launch: w[k][h] fp32 -> wt[mat][h][k] bf16
// ---------------------------------------------------------------------------
__global__ __launch_bounds__(256) void k_wt_all(
    const float* __restrict__ w0, const float* __restrict__ w1,
    const float* __restrict__ w2, const float* __restrict__ w3,
    const float* __restrict__ w4, const float* __restrict__ w5,
    unsigned short* __restrict__ wt) {
    int bid = blockIdx.x;
    int mat = bid >> 6;
    const float* w = (mat == 0) ? w0 : (mat == 1) ? w1 : (mat == 2) ? w2
                   : (mat == 3) ? w3 : (mat == 4) ? w4 : w5;
    int idx = (bid & 63) * 256 + threadIdx.x;   // 0..16383
    int d = idx >> 7, h = idx & 127;
    wt[mat * 16384 + h * 128 + d] = f2b(w[idx]);
}

// ---------------------------------------------------------------------------
// LN1 streaming: 2 rows per wave (32 lanes each), float4/lane in, 4xbf16 out.
// ---------------------------------------------------------------------------
__global__ __launch_bounds__(256) void k_ln1(const float* __restrict__ x,
                                             const float* __restrict__ sc,
                                             const float* __restrict__ bi,
                                             unsigned short* __restrict__ xn) {
    int t = threadIdx.x;
    int l = t & 31;
    size_t row = (size_t)blockIdx.x * 8 + (t >> 5);
    float4 v = *(const float4*)(x + row * DMODEL + l * 4);
    float s  = v.x + v.y + v.z + v.w;
    float sq = v.x * v.x + v.y * v.y + v.z * v.z + v.w * v.w;
    #pragma unroll
    for (int m = 1; m < 32; m <<= 1) {   // stays within each 32-lane half
        s  += __shfl_xor(s, m);
        sq += __shfl_xor(sq, m);
    }
    float mean = s * (1.f / 128.f);
    float var  = sq * (1.f / 128.f) - mean * mean;
    float inv  = rsqrtf(var + 1e-6f);
    float4 scv = *(const float4*)(sc + l * 4);
    float4 biv = *(const float4*)(bi + l * 4);
    unsigned long long o = 0;
    o |= (unsigned long long)f2b((v.x - mean) * inv * scv.x + biv.x);
    o |= (unsigned long long)f2b((v.y - mean) * inv * scv.y + biv.y) << 16;
    o |= (unsigned long long)f2b((v.z - mean) * inv * scv.z + biv.z) << 32;
    o |= (unsigned long long)f2b((v.w - mean) * inv * scv.w + biv.w) << 48;
    *(unsigned long long*)(xn + row * DMODEL + l * 4) = o;
}

// ---------------------------------------------------------------------------
// Projections. Block (a0,b): A-tile (64 rows x 128k) staged once in padded
// LDS (one barrier); B-fragments direct global->VGPR (L2-hot, dbuf one matrix
// ahead). og epilogue bounced through LDS for full-line coalesced stores.
// ---------------------------------------------------------------------------
__global__ __launch_bounds__(256, 2) void k_proj(
    const unsigned short* __restrict__ xn,
    const float* __restrict__ src_mask,
    const unsigned short* __restrict__ wt,  // wl,wlg,wr,wrg,wog (16384 each)
    const float* __restrict__ bl,  const float* __restrict__ blg,
    const float* __restrict__ br,  const float* __restrict__ brg,
    const float* __restrict__ bog,
    unsigned short* __restrict__ left_t,
    unsigned short* __restrict__ right_t,
    unsigned short* __restrict__ og) {
    __shared__ __align__(16) unsigned short As[64 * 136];
    const int t = threadIdx.x;
    const int lane = t & 63;
    const int wv = t >> 6;
    const int a0 = blockIdx.x * 64;
    const int b  = blockIdx.y;
    const int n0 = wv * 32;

    // ---- B dbuf: start first two matrices immediately ----
    short8 bfA[2][4], bfB[2][4];
    auto loadB = [&](short8 (&dst)[2][4], int mat) {
        const unsigned short* base = wt + mat * 16384 + (lane >> 4) * 8;
        #pragma unroll
        for (int nf = 0; nf < 2; ++nf)
            #pragma unroll
            for (int kc = 0; kc < 4; ++kc)
                dst[nf][kc] = *(const short8*)(
                    base + (n0 + nf * 16 + (lane & 15)) * 128 + kc * 32);
    };
    loadB(bfA, 0);
    loadB(bfB, 1);

    // ---- stage A tile: 64 rows x 256B, padded stride 136 shorts ----
    #pragma unroll
    for (int it = 0; it < 4; ++it) {
        int idx = it * 256 + t;
        int row = idx >> 4, c = idx & 15;
        *(short8*)(&As[row * 136 + c * 8]) =
            *(const short8*)(xn + ((size_t)(a0 + row) * NSEQ + b) * DMODEL + c * 8);
    }
    __syncthreads();

    // ---- hoist A fragments (shared across all 5 matrices) ----
    short8 af[4][4];   // [mf][kc]
    #pragma unroll
    for (int mf = 0; mf < 4; ++mf)
        #pragma unroll
        for (int kc = 0; kc < 4; ++kc)
            af[mf][kc] = *(const short8*)(
                &As[(mf * 16 + (lane & 15)) * 136 + kc * 32 + (lane >> 4) * 8]);

    f32x4 acc0[4][2], acc1[4][2];
    float smb = src_mask[b];

    auto mmat = [&](f32x4 (&acc)[4][2], short8 (&bf)[2][4]) {
        #pragma unroll
        for (int mf = 0; mf < 4; ++mf)
            #pragma unroll
            for (int nf = 0; nf < 2; ++nf)
                acc[mf][nf] = f32x4{0.f, 0.f, 0.f, 0.f};
        #pragma unroll
        for (int kc = 0; kc < 4; ++kc)
            #pragma unroll
            for (int mf = 0; mf < 4; ++mf)
                #pragma unroll
                for (int nf = 0; nf < 2; ++nf)
                    acc[mf][nf] = __builtin_amdgcn_mfma_f32_16x16x32_bf16(
                        af[mf][kc], bf[nf][kc], acc[mf][nf], 0, 0, 0);
    };
    auto epi_pair = [&](const float* b1, const float* b2, unsigned short* dst) {
        #pragma unroll
        for (int nf = 0; nf < 2; ++nf) {
            int h = n0 + nf * 16 + (lane & 15);
            float b1v = b1[h], b2v = b2[h];
            #pragma unroll
            for (int mf = 0; mf < 4; ++mf) {
                int abase = a0 + mf * 16 + ((lane >> 4) << 2);
                unsigned long long pv64 = 0;
                #pragma unroll
                for (int j = 0; j < 4; ++j) {
                    float pv = acc0[mf][nf][j] + b1v;
                    float gv = acc1[mf][nf][j] + b2v;
                    float mk = src_mask[abase + j] * smb;
                    unsigned long long q = f2b(pv * mk * sigmoidf_(gv));
                    pv64 |= q << (16 * j);
                }
                *(unsigned long long*)(dst + (size_t)h * NN + (size_t)b * NSEQ + abase) = pv64;
            }
        }
    };

    // order: 0=wl(acc0) 1=wlg(acc1) -> left; 2=wr 3=wrg -> right; 4=wog
    mmat(acc0, bfA);
    loadB(bfA, 2);
    mmat(acc1, bfB);
    loadB(bfB, 3);
    epi_pair(bl, blg, left_t);
    mmat(acc0, bfA);
    loadB(bfA, 4);
    mmat(acc1, bfB);
    epi_pair(br, brg, right_t);
    mmat(acc0, bfA);

    // og epilogue via LDS (As dead) for full-line stores: rows are 256B in og.
    __syncthreads();   // all waves done reading As fragments
    #pragma unroll
    for (int nf = 0; nf < 2; ++nf) {
        int h = n0 + nf * 16 + (lane & 15);
        float bv = bog[h];
        #pragma unroll
        for (int mf = 0; mf < 4; ++mf) {
            int rloc = mf * 16 + ((lane >> 4) << 2);
            #pragma unroll
            for (int j = 0; j < 4; ++j)
                As[(rloc + j) * 136 + h] = f2b(sigmoidf_(acc0[mf][nf][j] + bv));
        }
    }
    __syncthreads();
    #pragma unroll
    for (int it = 0; it < 4; ++it) {
        int idx = it * 256 + t;
        int row = idx >> 4, c = idx & 15;
        *(short8*)(og + ((size_t)(a0 + row) * NSEQ + b) * DMODEL + c * 8) =
            *(const short8*)(&As[row * 136 + c * 8]);
    }
}

// ---------------------------------------------------------------------------
// Einsum: per d-plane GEMM C[i][j] = sum_k A[i][k]*B[j][k].
// 128x128 tile, BK=32, double-buffered padded LDS (stride 36), 1 barrier/iter,
// next-tile loads issued before current compute. XCD plane locality swizzle.
// ---------------------------------------------------------------------------
__global__ __launch_bounds__(256) void k_einsum(
    const unsigned short* __restrict__ lt,
    const unsigned short* __restrict__ rt,
    unsigned short* __restrict__ mid) {
    __shared__ __align__(16) unsigned short As[2][128 * 36];
    __shared__ __align__(16) unsigned short Bs[2][128 * 36];
    const int t = threadIdx.x, lane = t & 63, wv = t >> 6;
    const int bid = blockIdx.x;
    const int xcd = bid & 7, slot = bid >> 3;
    const int d = xcd * 16 + (slot >> 4);
    const int tile = slot & 15;
    const int i0 = (tile >> 2) * 128, j0 = (tile & 3) * 128;
    const int m0 = (wv >> 1) * 64, n0 = (wv & 1) * 64;
    const unsigned short* Ag = lt + (size_t)d * NN;
    const unsigned short* Bg = rt + (size_t)d * NN;

    const int row0 = t >> 2, sub0 = t & 3;          // chunk 0 of this thread
    const int row1 = (256 + t) >> 2, sub1 = t & 3;  // chunk 1

    short8 ra[2], rb[2];
    auto loadTile = [&](int k0) {
        ra[0] = *(const short8*)(Ag + (size_t)(i0 + row0) * NSEQ + k0 + sub0 * 8);
        rb[0] = *(const short8*)(Bg + (size_t)(j0 + row0) * NSEQ + k0 + sub0 * 8);
        ra[1] = *(const short8*)(Ag + (size_t)(i0 + row1) * NSEQ + k0 + sub1 * 8);
        rb[1] = *(const short8*)(Bg + (size_t)(j0 + row1) * NSEQ + k0 + sub1 * 8);
    };
    auto writeTile = [&](int buf) {
        *(short8*)(&As[buf][row0 * 36 + sub0 * 8]) = ra[0];
        *(short8*)(&Bs[buf][row0 * 36 + sub0 * 8]) = rb[0];
        *(short8*)(&As[buf][row1 * 36 + sub1 * 8]) = ra[1];
        *(short8*)(&Bs[buf][row1 * 36 + sub1 * 8]) = rb[1];
    };

    f32x4 acc[4][4];
    #pragma unroll
    for (int mf = 0; mf < 4; ++mf)
        #pragma unroll
        for (int nf = 0; nf < 4; ++nf)
            acc[mf][nf] = f32x4{0.f, 0.f, 0.f, 0.f};

    loadTile(0);
    writeTile(0);
    int cur = 0;
    const int ko = (lane >> 4) * 8;
    for (int it = 0; it < 16; ++it) {
        __syncthreads();                    // buf[cur] visible to all
        if (it < 15) loadTile((it + 1) * 32);   // issue early; latency hides under MFMA
        short8 af[4], bf[4];
        #pragma unroll
        for (int mf = 0; mf < 4; ++mf)
            af[mf] = *(const short8*)(&As[cur][(m0 + mf * 16 + (lane & 15)) * 36 + ko]);
        #pragma unroll
        for (int nf = 0; nf < 4; ++nf)
            bf[nf] = *(const short8*)(&Bs[cur][(n0 + nf * 16 + (lane & 15)) * 36 + ko]);
        #pragma unroll
        for (int mf = 0; mf < 4; ++mf)
            #pragma unroll
            for (int nf = 0; nf < 4; ++nf)
                acc[mf][nf] = __builtin_amdgcn_mfma_f32_16x16x32_bf16(
                    af[mf], bf[nf], acc[mf][nf], 0, 0, 0);
        if (it < 15) writeTile(cur ^ 1);    // after compute; vmcnt waited by compiler
        cur ^= 1;
    }
    unsigned short* out = mid + (size_t)d * NN;
    #pragma unroll
    for (int mf = 0; mf < 4; ++mf) {
        int rbase = i0 + m0 + mf * 16 + ((lane >> 4) << 2);
        #pragma unroll
        for (int nf = 0; nf < 4; ++nf) {
            int col = j0 + n0 + nf * 16 + (lane & 15);
            #pragma unroll
            for (int j = 0; j < 4; ++j)
                out[(size_t)(rbase + j) * NSEQ + col] = f2b(acc[mf][nf][j]);
        }
    }
}

// ---------------------------------------------------------------------------
// LN2*gate. Thread = position; whole 128-d row in 64 packed VGPRs (mid read
// once, coalesced). Output via LDS for contiguous coalesced stores.
// ---------------------------------------------------------------------------
__global__ __launch_bounds__(128) void k_ln2gate(
    const unsigned short* __restrict__ mid,
    const unsigned short* __restrict__ og,
    const float* __restrict__ sc, const float* __restrict__ bi,
    unsigned short* __restrict__ g) {
    __shared__ __align__(16) unsigned short lo[128 * 136];
    const int t = threadIdx.x;
    const size_t p0 = (size_t)blockIdx.x * 128;
    const size_t p = p0 + t;

    unsigned int vals[64];
    float s = 0.f, sq = 0.f;
    #pragma unroll
    for (int d2 = 0; d2 < 64; ++d2) {
        unsigned int a = mid[(size_t)(2 * d2)     * NN + p];
        unsigned int c = mid[(size_t)(2 * d2 + 1) * NN + p];
        vals[d2] = a | (c << 16);
        float fa = b2f((unsigned short)a), fc = b2f((unsigned short)c);
        s += fa + fc; sq += fa * fa + fc * fc;
    }
    float mean = s * (1.f / 128.f);
    float var  = sq * (1.f / 128.f) - mean * mean;
    float inv  = rsqrtf(var + 1e-6f);
    #pragma unroll
    for (int c = 0; c < 16; ++c) {
        short8 ov = *(const short8*)(og + p * DMODEL + c * 8);
        short8 r8;
        #pragma unroll
        for (int e = 0; e < 8; ++e) {
            int d = c * 8 + e;
            unsigned int w = vals[d >> 1];
            float v = b2f((unsigned short)((d & 1) ? (w >> 16) : (w & 0xffff)));
            float y = (v - mean) * inv * sc[d] + bi[d];
            r8[e] = (short)f2b(y * b2f((unsigned short)ov[e]));
        }
        *(short8*)(&lo[t * 136 + c * 8]) = r8;
    }
    __syncthreads();
    #pragma unroll
    for (int i = 0; i < 16; ++i) {
        int idx = i * 128 + t;
        int row = idx >> 4, ch = idx & 15;
        *(short8*)(g + (p0 + row) * DMODEL + ch * 8) =
            *(const short8*)(&lo[row * 136 + ch * 8]);
    }
}

// ---------------------------------------------------------------------------
// Output projection: out = g @ wo + bo (fp32 out). 64-row tiles, full N=128.
// ---------------------------------------------------------------------------
__global__ __launch_bounds__(256) void k_out(
    const unsigned short* __restrict__ g,
    const unsigned short* __restrict__ wt_o,
    const float* __restrict__ bo,
    float* __restrict__ out) {
    __shared__ __align__(16) unsigned short As[64 * 136];
    __shared__ __align__(16) unsigned short Bs[128 * 136];
    const int t = threadIdx.x, lane = t & 63, wv = t >> 6;
    const size_t r0 = (size_t)blockIdx.x * 64;
    const int n0 = wv * 32;
    for (int it = 0; it < 4; ++it) {
        int idx = it * 256 + t;
        int row = idx >> 4, c = idx & 15;
        *(short8*)(&As[row * 136 + c * 8]) =
            *(const short8*)(g + (r0 + row) * DMODEL + c * 8);
    }
    for (int it = 0; it < 8; ++it) {
        int idx = it * 256 + t;
        int h = idx >> 4, c = idx & 15;
        *(short8*)(&Bs[h * 136 + c * 8]) = *(const short8*)(wt_o + h * 128 + c * 8);
    }
    __syncthreads();
    f32x4 acc[4][2];
    #pragma unroll
    for (int mf = 0; mf < 4; ++mf)
        #pragma unroll
        for (int nf = 0; nf < 2; ++nf)
            acc[mf][nf] = f32x4{0.f, 0.f, 0.f, 0.f};
    #pragma unroll
    for (int kc = 0; kc < 4; ++kc) {
        int ko = kc * 32 + (lane >> 4) * 8;
        short8 af[4], bf[2];
        #pragma unroll
        for (int mf = 0; mf < 4; ++mf)
            af[mf] = *(const short8*)(&As[(mf * 16 + (lane & 15)) * 136 + ko]);
        #pragma unroll
        for (int nf = 0; nf < 2; ++nf)
            bf[nf] = *(const short8*)(&Bs[(n0 + nf * 16 + (lane & 15)) * 136 + ko]);
        #pragma unroll
        for (int mf = 0; mf < 4; ++mf)
            #pragma unroll
            for (int nf = 0; nf < 2; ++nf)
                acc[mf][nf] = __builtin_amdgcn_mfma_f32_16x16x32_bf16(
                    af[mf], bf[nf], acc[mf][nf], 0, 0, 0);
    }
    #pragma unroll
    for (int nf = 0; nf < 2; ++nf) {
        int n = n0 + nf * 16 + (lane & 15);
        float bv = bo[n];
        #pragma unroll
        for (int mf = 0; mf < 4; ++mf) {
            int rb = mf * 16 + ((lane >> 4) << 2);
            #pragma unroll
            for (int j = 0; j < 4; ++j)
                out[(r0 + rb + j) * DMODEL + n] = acc[mf][nf][j] + bv;
        }
    }
}

// ---------------------------------------------------------------------------
extern "C" void kernel_launch(void* const* d_in, const int* in_sizes, int n_in,
                              void* d_out, int out_size, void* d_ws, size_t ws_size,
                              hipStream_t stream) {
    const float* x    = (const float*)d_in[0];
    const float* sm   = (const float*)d_in[1];
    const float* ln1s = (const float*)d_in[2];
    const float* ln1b = (const float*)d_in[3];
    const float* wl   = (const float*)d_in[4];
    const float* bl   = (const float*)d_in[5];
    const float* wr   = (const float*)d_in[6];
    const float* br   = (const float*)d_in[7];
    const float* wlg  = (const float*)d_in[8];
    const float* blg  = (const float*)d_in[9];
    const float* wrg  = (const float*)d_in[10];
    const float* brg  = (const float*)d_in[11];
    const float* wog  = (const float*)d_in[12];
    const float* bog  = (const float*)d_in[13];
    const float* ln2s = (const float*)d_in[14];
    const float* ln2b = (const float*)d_in[15];
    const float* wo   = (const float*)d_in[16];
    const float* bo   = (const float*)d_in[17];
    float* out = (float*)d_out;

    // workspace: wt(196608B) | xn | lt | rt | og | mid   (5 x 64MB)
    char* ws = (char*)d_ws;
    unsigned short* wt  = (unsigned short*)ws;
    unsigned short* xn  = (unsigned short*)(ws + 196608);
    unsigned short* lt  = (unsigned short*)(ws + 196608 + 1ull * 67108864);
    unsigned short* rt  = (unsigned short*)(ws + 196608 + 2ull * 67108864);
    unsigned short* ogb = (unsigned short*)(ws + 196608 + 3ull * 67108864);
    unsigned short* mid = (unsigned short*)(ws + 196608 + 4ull * 67108864);
    unsigned short* gb  = xn;   // reuse: xn dead after k_proj

    k_wt_all<<<384, 256, 0, stream>>>(wl, wlg, wr, wrg, wog, wo, wt);
    k_ln1<<<32768, 256, 0, stream>>>(x, ln1s, ln1b, xn);
    k_proj<<<dim3(8, 512), 256, 0, stream>>>(xn, sm, wt,
                                             bl, blg, br, brg, bog, lt, rt, ogb);
    k_einsum<<<2048, 256, 0, stream>>>(lt, rt, mid);
    k_ln2gate<<<2048, 128, 0, stream>>>(mid, ogb, ln2s, ln2b, gb);
    k_out<<<4096, 256, 0, stream>>>(gb, wt + 5 * 16384, bo, out);
}